// Round 7
// baseline (455.719 us; speedup 1.0000x reference)
//
#include <hip/hip_runtime.h>
#include <math.h>

// Problem constants
static const int kB = 32;
static const int kL = 1024;
static const int kH = 512;
static const int kN = 64;
static const int kNL = 4;
static const int kNFFT = 2048;

#define TWO_PI 6.283185307179586476925286766559

typedef float v2f __attribute__((ext_vector_type(2)));

// complex mul: a*b
__device__ __forceinline__ v2f cmul(v2f a, v2f b) {
    v2f axx = __builtin_shufflevector(a, a, 0, 0);
    v2f ayy = __builtin_shufflevector(a, a, 1, 1);
    v2f byx = __builtin_shufflevector(b, b, 1, 0);
    v2f t = ayy * byx;
    t.x = -t.x;
    return axx * b + t;     // v_pk_fma_f32
}

// complex mul by conjugate: a*conj(b)  (same 3-op shape as cmul)
__device__ __forceinline__ v2f cmulc(v2f a, v2f b) {
    v2f axx = __builtin_shufflevector(a, a, 0, 0);
    v2f ayy = __builtin_shufflevector(a, a, 1, 1);
    v2f byx = __builtin_shufflevector(b, b, 1, 0);
    v2f t = axx * b;        // (a.x b.x, a.x b.y)
    t.y = -t.y;
    return ayy * byx + t;   // (a.y b.y + a.x b.x, a.y b.x - a.x b.y)
}

// j3 = fwd ? (t.y, -t.x) : (-t.y, t.x)
template<bool INV>
__device__ __forceinline__ v2f jrot(v2f t) {
    v2f r = __builtin_shufflevector(t, t, 1, 0);
    if (!INV) { r.y = -r.y; } else { r.x = -r.x; }
    return r;
}

// LDS swizzle: element i lives at i + (i>>4). All patterns land 4 lanes per
// bank-pair for b64 (bandwidth-optimal; residual SQ_LDS_BANK_CONFLICT count
// at this level is an artifact, measured R4/R5 identical).
#define LDSZ 2176
__device__ __forceinline__ constexpr int swoff(int LGM, int u) {
    return (LGM == 0) ? u : (LGM == 3) ? (8 * u + (u >> 1)) : (68 * u);
}

// ---------------------------------------------------------------------------
// 8-point DFT in registers, natural order. INV=true -> conjugate transform.
// ---------------------------------------------------------------------------
template<bool INV>
__device__ __forceinline__ void dft8(const v2f c[8], v2f y[8]) {
    const float s = 0.70710678118654752440f;
    v2f t0 = c[0] + c[4], t1 = c[0] - c[4];
    v2f t2 = c[2] + c[6], t3 = c[2] - c[6];
    v2f e0 = t0 + t2, e2 = t0 - t2;
    v2f j3 = jrot<INV>(t3);
    v2f e1 = t1 + j3, e3 = t1 - j3;

    t0 = c[1] + c[5]; t1 = c[1] - c[5];
    t2 = c[3] + c[7]; t3 = c[3] - c[7];
    v2f o0 = t0 + t2, o2 = t0 - t2;
    v2f j3o = jrot<INV>(t3);
    v2f o1 = t1 + j3o, o3 = t1 - j3o;

    if (!INV) {
        v2f r1 = __builtin_shufflevector(o1, o1, 1, 0);
        o1 = s * (v2f){o1.x + r1.x, o1.y - r1.y};          // s(x+y, y-x)
        v2f r2 = __builtin_shufflevector(o2, o2, 1, 0);
        o2 = (v2f){r2.x, -r2.y};                            // (y, -x)
        v2f r3 = __builtin_shufflevector(o3, o3, 1, 0);
        o3 = s * (v2f){r3.x - o3.x, -r3.y - o3.y};          // s(y-x, -(x+y))
    } else {
        v2f r1 = __builtin_shufflevector(o1, o1, 1, 0);
        o1 = s * (v2f){o1.x - r1.x, o1.y + r1.y};          // s(x-y, x+y)
        v2f r2 = __builtin_shufflevector(o2, o2, 1, 0);
        o2 = (v2f){-r2.x, r2.y};                            // (-y, x)
        v2f r3 = __builtin_shufflevector(o3, o3, 1, 0);
        o3 = s * (v2f){-(o3.x + r3.x), r3.y - o3.y};        // (-s(x+y), s(x-y))
    }
    y[0] = e0 + o0; y[4] = e0 - o0;
    y[1] = e1 + o1; y[5] = e1 - o1;
    y[2] = e2 + o2; y[6] = e2 - o2;
    y[3] = e3 + o3; y[7] = e3 - o3;
}

// Forward dft8 with inputs c[4..7] == 0 (zero-padded half).
__device__ __forceinline__ void dft8h(const v2f c[4], v2f y[8]) {
    const float s = 0.70710678118654752440f;
    v2f e0 = c[0] + c[2], e2 = c[0] - c[2];
    v2f j  = jrot<false>(c[2]);
    v2f e1 = c[0] + j, e3 = c[0] - j;
    v2f o0 = c[1] + c[3], o2 = c[1] - c[3];
    v2f jo = jrot<false>(c[3]);
    v2f o1 = c[1] + jo, o3 = c[1] - jo;

    v2f r1 = __builtin_shufflevector(o1, o1, 1, 0);
    o1 = s * (v2f){o1.x + r1.x, o1.y - r1.y};
    v2f r2 = __builtin_shufflevector(o2, o2, 1, 0);
    o2 = (v2f){r2.x, -r2.y};
    v2f r3 = __builtin_shufflevector(o3, o3, 1, 0);
    o3 = s * (v2f){r3.x - o3.x, -r3.y - o3.y};

    y[0] = e0 + o0; y[4] = e0 - o0;
    y[1] = e1 + o1; y[5] = e1 - o1;
    y[2] = e2 + o2; y[6] = e2 - o2;
    y[3] = e3 + o3; y[7] = e3 - o3;
}

// Stockham radix-8 stage: dst[j*8m + i + u*m] = W_N^{jm*u} * y[u]
// Twiddles from a precomputed global table (L2-resident, shared by all wgs):
// tw[(tsel*256 + tid)*7 + (u-1)], tsel = {LGM0->0, LGM3->1, LGM6->2}.
// Inverse uses the SAME table via cmulc (y * conj(w)).
template<bool INV, int LGM>
__device__ __forceinline__ void stage8_write(v2f* lds, int tid, v2f y[8],
                                             const v2f* __restrict__ tw) {
    const int m = 1 << LGM;
    const int tsel = (LGM == 0) ? 0 : (LGM == 3) ? 1 : 2;
    const v2f* twp = tw + (tsel * 256 + tid) * 7;
    v2f w1 = twp[0], w2 = twp[1], w3 = twp[2], w4 = twp[3];
    v2f w5 = twp[4], w6 = twp[5], w7 = twp[6];
    int base = ((tid >> LGM) << (LGM + 3)) + (tid & (m - 1));
    int swb = base + (base >> 4);
    lds[swb + swoff(LGM, 0)] = y[0];
    if (!INV) {
        lds[swb + swoff(LGM, 1)] = cmul(w1, y[1]);
        lds[swb + swoff(LGM, 2)] = cmul(w2, y[2]);
        lds[swb + swoff(LGM, 3)] = cmul(w3, y[3]);
        lds[swb + swoff(LGM, 4)] = cmul(w4, y[4]);
        lds[swb + swoff(LGM, 5)] = cmul(w5, y[5]);
        lds[swb + swoff(LGM, 6)] = cmul(w6, y[6]);
        lds[swb + swoff(LGM, 7)] = cmul(w7, y[7]);
    } else {
        lds[swb + swoff(LGM, 1)] = cmulc(y[1], w1);
        lds[swb + swoff(LGM, 2)] = cmulc(y[2], w2);
        lds[swb + swoff(LGM, 3)] = cmulc(y[3], w3);
        lds[swb + swoff(LGM, 4)] = cmulc(y[4], w4);
        lds[swb + swoff(LGM, 5)] = cmulc(y[5], w5);
        lds[swb + swoff(LGM, 6)] = cmulc(y[6], w6);
        lds[swb + swoff(LGM, 7)] = cmulc(y[7], w7);
    }
}

__device__ __forceinline__ void read8(const v2f* lds, int swb, v2f c[8]) {
#pragma unroll
    for (int s = 0; s < 8; ++s) c[s] = lds[swb + 272 * s];
}

// gelu (tanh approx) on a pair
__device__ __forceinline__ v2f gelu2(v2f v) {
    v2f v2 = v * v;
    v2f q = v2 * 0.044715f + 1.0f;
    v2f z = v * q * 1.5957691216057308f;
    v2f e;
    e.x = __expf(z.x); e.y = __expf(z.y);
    v2f den = e + 1.0f;
    v2f r;
    r.x = __builtin_amdgcn_rcpf(den.x);
    r.y = __builtin_amdgcn_rcpf(den.y);
    return v - v * r;
}

// ---------------------------------------------------------------------------
// Twiddle table fill: tw[(tsel*256+tid)*7 + u-1] = W_2048^(jm*u), fwd sign.
// 1 wg, 256 threads; double-precision sin/cos (tiny, runs once).
// ---------------------------------------------------------------------------
__global__ __launch_bounds__(256) void twfill_kernel(v2f* __restrict__ tw)
{
    int tid = threadIdx.x;
    const int lgms[3] = {0, 3, 6};
#pragma unroll
    for (int t = 0; t < 3; ++t) {
        int m = 1 << lgms[t];
        int jm = tid & ~(m - 1);
        for (int u = 1; u <= 7; ++u) {
            double ang = -TWO_PI * (double)(jm * u) / 2048.0;
            tw[(t * 256 + tid) * 7 + (u - 1)] = (v2f){(float)cos(ang), (float)sin(ang)};
        }
    }
}

// ---------------------------------------------------------------------------
// Embedding gather with 64x64 tile transpose: act[b][h][l] = emb[x[b][l]][h]
// ---------------------------------------------------------------------------
__global__ __launch_bounds__(256) void embed_kernel(const int* __restrict__ x,
                                                    const float* __restrict__ emb,
                                                    float* __restrict__ act)
{
    __shared__ float tile[64][65];
    int hb = blockIdx.x, lb = blockIdx.y, b = blockIdx.z;
    int h0 = hb * 64, l0 = lb * 64;
    int tid = threadIdx.x;
#pragma unroll
    for (int k = 0; k < 16; ++k) {
        int idx = (k << 8) + tid;
        int li = idx >> 6, hi = idx & 63;
        int xv = x[b * kL + l0 + li];
        tile[li][hi] = emb[(size_t)xv * kH + h0 + hi];
    }
    __syncthreads();
#pragma unroll
    for (int k = 0; k < 16; ++k) {
        int idx = (k << 8) + tid;
        int hi = idx >> 6, li = idx & 63;
        act[((size_t)b * kH + h0 + hi) * kL + l0 + li] = tile[li][hi];
    }
}

// ---------------------------------------------------------------------------
// SSM kernel K[h][l] + forward FFT -> Khat (pre-scaled by 1/2048).
// grid: (h=512, layers); layer = layer0 + blockIdx.y
// ---------------------------------------------------------------------------
__global__ __launch_bounds__(256) void kcomp_kernel(const float* __restrict__ log_dt,
                                                    const float* __restrict__ A_log,
                                                    const float* __restrict__ A_imag,
                                                    const float* __restrict__ C_re,
                                                    const float* __restrict__ C_im,
                                                    v2f* __restrict__ Khat,
                                                    const v2f* __restrict__ tw,
                                                    int layer0, int out_stride)
{
    __shared__ v2f lds[LDSZ];
    __shared__ float dre_s[kN], g2re_s[kN], g2im_s[kN], hi_s[kN], lo_s[kN];
    __shared__ v2f w256_s[kN];

    int h = blockIdx.x, tid = threadIdx.x;
    int layer = layer0 + blockIdx.y;
    int swbase = tid + (tid >> 4);
    const size_t po = (size_t)layer * kH + h;

    if (tid < kN) {
        int n = tid;
        float dt  = expf(log_dt[po]);
        float Are = -expf(A_log[po * kN + n]);
        float Aim = A_imag[po * kN + n];
        float dre = dt * Are;
        float dim = dt * Aim;
        float er = expf(dre);
        float sw, cw;
        sincosf(dim, &sw, &cw);
        float emr = er * cw - 1.0f, emi = er * sw;
        float inv = 1.0f / (Are * Are + Aim * Aim);
        float air = Are * inv, aii = -Aim * inv;
        float br = emr * air - emi * aii;
        float bi = emr * aii + emi * air;
        float cr = C_re[po * kN + n], ci = C_im[po * kN + n];
        dre_s[n]  = dre;
        g2re_s[n] = 2.0f * (cr * br - ci * bi);
        g2im_s[n] = 2.0f * (cr * bi + ci * br);
        double dimrev = (double)dim * (1.0 / TWO_PI);
        float drf = (float)dimrev;
        float hi = __uint_as_float(__float_as_uint(drf) & 0xFFFFF000u);
        hi_s[n] = hi;
        lo_s[n] = (float)(dimrev - (double)hi);
        float mag256 = __expf(dre * 256.0f);
        double r2 = dimrev * 256.0;
        r2 -= floor(r2);
        float fr2 = (float)r2;
        w256_s[n] = (v2f){mag256 * __builtin_amdgcn_cosf(fr2),
                          mag256 * __builtin_amdgcn_sinf(fr2)};
    }
    __syncthreads();

    // K at l = tid + 256*s  (matches FFT stage-1 register layout)
    float acc0 = 0.f, acc1 = 0.f, acc2 = 0.f, acc3 = 0.f;
    const float lf = (float)tid;
    for (int n = 0; n < kN; ++n) {
        float dre  = dre_s[n];
        float g2re = g2re_s[n], g2im = g2im_s[n];
        float t1 = hi_s[n] * lf;            // exact
        float r1 = t1 - floorf(t1);
        float rv = r1 + lo_s[n] * lf;
        rv -= floorf(rv);                   // revolutions in [0,1)
        float mag = __expf(dre * lf);
        float sp = __builtin_amdgcn_sinf(rv);
        float cp = __builtin_amdgcn_cosf(rv);
        float pzx = mag * cp, pzy = mag * sp;
        v2f w = w256_s[n];
        float tx;
        acc0 += g2re * pzx - g2im * pzy;
        tx = pzx * w.x - pzy * w.y; pzy = pzx * w.y + pzy * w.x; pzx = tx;
        acc1 += g2re * pzx - g2im * pzy;
        tx = pzx * w.x - pzy * w.y; pzy = pzx * w.y + pzy * w.x; pzx = tx;
        acc2 += g2re * pzx - g2im * pzy;
        tx = pzx * w.x - pzy * w.y; pzy = pzx * w.y + pzy * w.x; pzx = tx;
        acc3 += g2re * pzx - g2im * pzy;
    }

    {   // forward stage 1 from registers (upper half zero)
        v2f c[4], y[8];
        c[0] = (v2f){acc0, 0.f}; c[1] = (v2f){acc1, 0.f};
        c[2] = (v2f){acc2, 0.f}; c[3] = (v2f){acc3, 0.f};
        dft8h(c, y);
        stage8_write<false, 0>(lds, tid, y, tw);
    }
    __syncthreads();
    {
        v2f c[8], y[8];
        read8(lds, swbase, c);
        __syncthreads();
        dft8<false>(c, y);
        stage8_write<false, 3>(lds, tid, y, tw);
    }
    __syncthreads();
    {
        v2f c[8], y[8];
        read8(lds, swbase, c);
        __syncthreads();
        dft8<false>(c, y);
        stage8_write<false, 6>(lds, tid, y, tw);
    }
    __syncthreads();
    {   // radix-4 final stage (m=512, j=0) -> global, natural order, *1/2048
        const float invn = 1.0f / (float)kNFFT;
        v2f* outp = Khat + (size_t)(layer * out_stride + h) * kNFFT;
#pragma unroll
        for (int r = 0; r < 2; ++r) {
            v2f c0 = lds[swbase + 272 * r];
            v2f c1 = lds[swbase + 272 * r + 544];
            v2f c2 = lds[swbase + 272 * r + 1088];
            v2f c3 = lds[swbase + 272 * r + 1632];
            v2f t0 = c0 + c2, t1 = c0 - c2;
            v2f t2 = c1 + c3, t3 = c1 - c3;
            v2f j3 = jrot<false>(t3);
            int q = tid + (r << 8);
            outp[q]        = (t0 + t2) * invn;
            outp[q + 512]  = (t1 + j3) * invn;
            outp[q + 1024] = (t0 - t2) * invn;
            outp[q + 1536] = (t1 - j3) * invn;
        }
    }
}

// ---------------------------------------------------------------------------
// Per-layer conv (R3-proven codegen): rows (2*pair,h),(2*pair+1,h) packed as
// one complex signal; us[] in registers; FFT -> *Khat -> IFFT -> +D*u -> gelu.
// grid: (h=512, pair=16), 256 threads
// ---------------------------------------------------------------------------
__global__ __launch_bounds__(256) void conv_kernel(float* __restrict__ act,
                                                   const v2f* __restrict__ Khat,
                                                   const v2f* __restrict__ tw,
                                                   const float* __restrict__ Dvec)
{
    __shared__ v2f lds[LDSZ];

    int h = blockIdx.x, pair = blockIdx.y, tid = threadIdx.x;
    int swbase = tid + (tid >> 4);
    float* rowa = act + ((size_t)(2 * pair) * kH + h) * kL;
    float* rowb = rowa + (size_t)kH * kL;

    v2f us[4];
#pragma unroll
    for (int s = 0; s < 4; ++s) {
        int l = tid + (s << 8);
        us[s] = (v2f){rowa[l], rowb[l]};
    }
    {
        v2f y[8];
        dft8h(us, y);
        stage8_write<false, 0>(lds, tid, y, tw);
    }
    __syncthreads();
    {
        v2f c[8], y[8];
        read8(lds, swbase, c);
        __syncthreads();
        dft8<false>(c, y);
        stage8_write<false, 3>(lds, tid, y, tw);
    }
    __syncthreads();
    {
        v2f c[8], y[8];
        read8(lds, swbase, c);
        __syncthreads();
        dft8<false>(c, y);
        stage8_write<false, 6>(lds, tid, y, tw);
    }
    __syncthreads();
    {
        v2f cc[2][4];
#pragma unroll
        for (int r = 0; r < 2; ++r)
#pragma unroll
            for (int s = 0; s < 4; ++s)
                cc[r][s] = lds[swbase + 272 * r + 544 * s];
        __syncthreads();
        const v2f* kh = Khat + (size_t)h * kNFFT;
#pragma unroll
        for (int r = 0; r < 2; ++r) {
            v2f t0 = cc[r][0] + cc[r][2], t1 = cc[r][0] - cc[r][2];
            v2f t2 = cc[r][1] + cc[r][3], t3 = cc[r][1] - cc[r][3];
            v2f j3 = jrot<false>(t3);
            int q = tid + (r << 8);
            int swq = swbase + 272 * r;
            lds[swq]        = cmul(t0 + t2, kh[q]);
            lds[swq + 544]  = cmul(t1 + j3, kh[q + 512]);
            lds[swq + 1088] = cmul(t0 - t2, kh[q + 1024]);
            lds[swq + 1632] = cmul(t1 - j3, kh[q + 1536]);
        }
    }
    __syncthreads();
    {
        v2f c[8], y[8];
        read8(lds, swbase, c);
        __syncthreads();
        dft8<true>(c, y);
        stage8_write<true, 0>(lds, tid, y, tw);
    }
    __syncthreads();
    {
        v2f c[8], y[8];
        read8(lds, swbase, c);
        __syncthreads();
        dft8<true>(c, y);
        stage8_write<true, 3>(lds, tid, y, tw);
    }
    __syncthreads();
    {
        v2f c[8], y[8];
        read8(lds, swbase, c);
        __syncthreads();
        dft8<true>(c, y);
        stage8_write<true, 6>(lds, tid, y, tw);
    }
    __syncthreads();
    {
        float Dh = Dvec[h];
#pragma unroll
        for (int r = 0; r < 2; ++r) {
            v2f c0 = lds[swbase + 272 * r];
            v2f c1 = lds[swbase + 272 * r + 544];
            v2f c2 = lds[swbase + 272 * r + 1088];
            v2f c3 = lds[swbase + 272 * r + 1632];
            v2f t0 = c0 + c2, t1 = c0 - c2;
            v2f t2 = c1 + c3, t3 = c1 - c3;
            v2f j3 = jrot<false>(t3);
            v2f y0 = t0 + t2;
            v2f y1 = t1 - j3;
            int l0 = tid + (r << 8);
            v2f g0 = gelu2(y0 + Dh * us[r]);
            v2f g1 = gelu2(y1 + Dh * us[r + 2]);
            rowa[l0]       = g0.x;
            rowb[l0]       = g0.y;
            rowa[l0 + 512] = g1.x;
            rowb[l0 + 512] = g1.y;
        }
    }
}

// ---------------------------------------------------------------------------
// Last-layer conv fused with mean-pool + fc: identical FFT body, but the
// epilogue accumulates gelu outputs and reduces to out[b] (no act store).
// grid: (h=512, pair=16), 256 threads
// ---------------------------------------------------------------------------
__global__ __launch_bounds__(256) void conv_final(const float* __restrict__ act,
                                                  const v2f* __restrict__ Khat,
                                                  const v2f* __restrict__ tw,
                                                  const float* __restrict__ Dvec,
                                                  const float* __restrict__ fc_w,
                                                  const float* __restrict__ fc_b,
                                                  float* __restrict__ out)
{
    __shared__ v2f lds[LDSZ];
    __shared__ v2f wred[4];

    int h = blockIdx.x, pair = blockIdx.y, tid = threadIdx.x;
    int swbase = tid + (tid >> 4);
    const float* rowa = act + ((size_t)(2 * pair) * kH + h) * kL;
    const float* rowb = rowa + (size_t)kH * kL;

    v2f us[4];
#pragma unroll
    for (int s = 0; s < 4; ++s) {
        int l = tid + (s << 8);
        us[s] = (v2f){rowa[l], rowb[l]};
    }
    {
        v2f y[8];
        dft8h(us, y);
        stage8_write<false, 0>(lds, tid, y, tw);
    }
    __syncthreads();
    {
        v2f c[8], y[8];
        read8(lds, swbase, c);
        __syncthreads();
        dft8<false>(c, y);
        stage8_write<false, 3>(lds, tid, y, tw);
    }
    __syncthreads();
    {
        v2f c[8], y[8];
        read8(lds, swbase, c);
        __syncthreads();
        dft8<false>(c, y);
        stage8_write<false, 6>(lds, tid, y, tw);
    }
    __syncthreads();
    {
        v2f cc[2][4];
#pragma unroll
        for (int r = 0; r < 2; ++r)
#pragma unroll
            for (int s = 0; s < 4; ++s)
                cc[r][s] = lds[swbase + 272 * r + 544 * s];
        __syncthreads();
        const v2f* kh = Khat + (size_t)h * kNFFT;
#pragma unroll
        for (int r = 0; r < 2; ++r) {
            v2f t0 = cc[r][0] + cc[r][2], t1 = cc[r][0] - cc[r][2];
            v2f t2 = cc[r][1] + cc[r][3], t3 = cc[r][1] - cc[r][3];
            v2f j3 = jrot<false>(t3);
            int q = tid + (r << 8);
            int swq = swbase + 272 * r;
            lds[swq]        = cmul(t0 + t2, kh[q]);
            lds[swq + 544]  = cmul(t1 + j3, kh[q + 512]);
            lds[swq + 1088] = cmul(t0 - t2, kh[q + 1024]);
            lds[swq + 1632] = cmul(t1 - j3, kh[q + 1536]);
        }
    }
    __syncthreads();
    {
        v2f c[8], y[8];
        read8(lds, swbase, c);
        __syncthreads();
        dft8<true>(c, y);
        stage8_write<true, 0>(lds, tid, y, tw);
    }
    __syncthreads();
    {
        v2f c[8], y[8];
        read8(lds, swbase, c);
        __syncthreads();
        dft8<true>(c, y);
        stage8_write<true, 3>(lds, tid, y, tw);
    }
    __syncthreads();
    {
        v2f c[8], y[8];
        read8(lds, swbase, c);
        __syncthreads();
        dft8<true>(c, y);
        stage8_write<true, 6>(lds, tid, y, tw);
    }
    __syncthreads();
    v2f p = (v2f){0.f, 0.f};
    {
        float Dh = Dvec[h];
#pragma unroll
        for (int r = 0; r < 2; ++r) {
            v2f c0 = lds[swbase + 272 * r];
            v2f c1 = lds[swbase + 272 * r + 544];
            v2f c2 = lds[swbase + 272 * r + 1088];
            v2f c3 = lds[swbase + 272 * r + 1632];
            v2f t0 = c0 + c2, t1 = c0 - c2;
            v2f t2 = c1 + c3, t3 = c1 - c3;
            v2f j3 = jrot<false>(t3);
            v2f y0 = t0 + t2;
            v2f y1 = t1 - j3;
            p += gelu2(y0 + Dh * us[r]);
            p += gelu2(y1 + Dh * us[r + 2]);
        }
    }
    // block reduce (64-lane waves) then one atomicAdd per output element
#pragma unroll
    for (int off = 32; off > 0; off >>= 1) {
        p.x += __shfl_down(p.x, off);
        p.y += __shfl_down(p.y, off);
    }
    if ((tid & 63) == 0) wred[tid >> 6] = p;
    __syncthreads();
    if (tid == 0) {
        v2f t = wred[0] + wred[1] + wred[2] + wred[3];
        float scale = fc_w[h] * (1.0f / (float)kL);
        float bias = (h == 0) ? fc_b[0] : 0.0f;
        atomicAdd(out + 2 * pair,     t.x * scale + bias);
        atomicAdd(out + 2 * pair + 1, t.y * scale + bias);
    }
}

// ---------------------------------------------------------------------------
extern "C" void kernel_launch(void* const* d_in, const int* in_sizes, int n_in,
                              void* d_out, int out_size, void* d_ws, size_t ws_size,
                              hipStream_t stream)
{
    const int*   x         = (const int*)d_in[0];
    const float* embedding = (const float*)d_in[1];
    const float* log_dt    = (const float*)d_in[2];
    const float* A_log     = (const float*)d_in[3];
    const float* A_imag    = (const float*)d_in[4];
    const float* C_re      = (const float*)d_in[5];
    const float* C_im      = (const float*)d_in[6];
    const float* Dv        = (const float*)d_in[7];
    const float* fc_w      = (const float*)d_in[8];
    const float* fc_b      = (const float*)d_in[9];
    float* out = (float*)d_out;

    char* ws = (char*)d_ws;
    const size_t tw_bytes   = 64 * 1024;                                  // 43 KB used
    const size_t act_bytes  = (size_t)kB * kH * kL * sizeof(float);       // 64 MiB
    const size_t khat_bytes = (size_t)kH * kNFFT * sizeof(float) * 2;     // 8 MiB / layer
    v2f*   tw   = (v2f*)ws;
    float* act  = (float*)(ws + tw_bytes);
    v2f*   Khat = (v2f*)(ws + tw_bytes + act_bytes);

    const bool multi = ws_size >= tw_bytes + act_bytes + kNL * khat_bytes;

    hipMemsetAsync(d_out, 0, (size_t)out_size * sizeof(float), stream);
    twfill_kernel<<<1, 256, 0, stream>>>(tw);
    embed_kernel<<<dim3(8, 16, 32), 256, 0, stream>>>(x, embedding, act);

    if (multi) {
        kcomp_kernel<<<dim3(kH, kNL), 256, 0, stream>>>(log_dt, A_log, A_imag,
                                                        C_re, C_im, Khat, tw, 0, kH);
        for (int layer = 0; layer < kNL - 1; ++layer) {
            conv_kernel<<<dim3(kH, kB / 2), 256, 0, stream>>>(
                act, Khat + (size_t)layer * kH * kNFFT, tw, Dv + layer * kH);
        }
        conv_final<<<dim3(kH, kB / 2), 256, 0, stream>>>(
            act, Khat + (size_t)(kNL - 1) * kH * kNFFT, tw,
            Dv + (kNL - 1) * kH, fc_w, fc_b, out);
    } else {
        for (int layer = 0; layer < kNL - 1; ++layer) {
            kcomp_kernel<<<dim3(kH, 1), 256, 0, stream>>>(log_dt, A_log, A_imag,
                                                          C_re, C_im, Khat, tw, layer, 0);
            conv_kernel<<<dim3(kH, kB / 2), 256, 0, stream>>>(act, Khat, tw, Dv + layer * kH);
        }
        kcomp_kernel<<<dim3(kH, 1), 256, 0, stream>>>(log_dt, A_log, A_imag,
                                                      C_re, C_im, Khat, tw, kNL - 1, 0);
        conv_final<<<dim3(kH, kB / 2), 256, 0, stream>>>(act, Khat, tw,
                                                         Dv + (kNL - 1) * kH, fc_w, fc_b, out);
    }
}

// Round 8
// 292.803 us; speedup vs baseline: 1.5564x; 1.5564x over previous
//
#include <hip/hip_runtime.h>
#include <math.h>

// Problem constants
static const int kB = 32;
static const int kL = 1024;
static const int kH = 512;
static const int kN = 64;
static const int kNL = 4;
static const int kNFFT = 2048;

#define TWO_PI 6.283185307179586476925286766559

typedef float v2f __attribute__((ext_vector_type(2)));

// complex mul: (a.x b.x - a.y b.y, a.x b.y + a.y b.x)
__device__ __forceinline__ v2f cmul(v2f a, v2f b) {
    v2f axx = __builtin_shufflevector(a, a, 0, 0);
    v2f ayy = __builtin_shufflevector(a, a, 1, 1);
    v2f byx = __builtin_shufflevector(b, b, 1, 0);
    v2f t = ayy * byx;
    t.x = -t.x;
    return axx * b + t;     // v_pk_fma_f32
}

// j3 = fwd ? (t.y, -t.x) : (-t.y, t.x)
template<bool INV>
__device__ __forceinline__ v2f jrot(v2f t) {
    v2f r = __builtin_shufflevector(t, t, 1, 0);
    if (!INV) { r.y = -r.y; } else { r.x = -r.x; }
    return r;
}

// LDS swizzle: element i lives at i + (i>>4). All patterns land 4 lanes per
// bank-pair for b64 (bandwidth-optimal; residual SQ_LDS_BANK_CONFLICT is an
// artifact — measured identical across R4/R5 while perf varied 3x).
#define LDSZ 2176
__device__ __forceinline__ constexpr int swoff(int LGM, int u) {
    return (LGM == 0) ? u : (LGM == 3) ? (8 * u + (u >> 1)) : (68 * u);
}

// ---------------------------------------------------------------------------
// 8-point DFT in registers, natural order. INV=true -> conjugate transform.
// ---------------------------------------------------------------------------
template<bool INV>
__device__ __forceinline__ void dft8(const v2f c[8], v2f y[8]) {
    const float s = 0.70710678118654752440f;
    v2f t0 = c[0] + c[4], t1 = c[0] - c[4];
    v2f t2 = c[2] + c[6], t3 = c[2] - c[6];
    v2f e0 = t0 + t2, e2 = t0 - t2;
    v2f j3 = jrot<INV>(t3);
    v2f e1 = t1 + j3, e3 = t1 - j3;

    t0 = c[1] + c[5]; t1 = c[1] - c[5];
    t2 = c[3] + c[7]; t3 = c[3] - c[7];
    v2f o0 = t0 + t2, o2 = t0 - t2;
    v2f j3o = jrot<INV>(t3);
    v2f o1 = t1 + j3o, o3 = t1 - j3o;

    if (!INV) {
        v2f r1 = __builtin_shufflevector(o1, o1, 1, 0);
        o1 = s * (v2f){o1.x + r1.x, o1.y - r1.y};          // s(x+y, y-x)
        v2f r2 = __builtin_shufflevector(o2, o2, 1, 0);
        o2 = (v2f){r2.x, -r2.y};                            // (y, -x)
        v2f r3 = __builtin_shufflevector(o3, o3, 1, 0);
        o3 = s * (v2f){r3.x - o3.x, -r3.y - o3.y};          // s(y-x, -(x+y))
    } else {
        v2f r1 = __builtin_shufflevector(o1, o1, 1, 0);
        o1 = s * (v2f){o1.x - r1.x, o1.y + r1.y};          // s(x-y, x+y)
        v2f r2 = __builtin_shufflevector(o2, o2, 1, 0);
        o2 = (v2f){-r2.x, r2.y};                            // (-y, x)
        v2f r3 = __builtin_shufflevector(o3, o3, 1, 0);
        o3 = s * (v2f){-(o3.x + r3.x), r3.y - o3.y};        // (-s(x+y), s(x-y))
    }
    y[0] = e0 + o0; y[4] = e0 - o0;
    y[1] = e1 + o1; y[5] = e1 - o1;
    y[2] = e2 + o2; y[6] = e2 - o2;
    y[3] = e3 + o3; y[7] = e3 - o3;
}

// Forward dft8 with inputs c[4..7] == 0 (zero-padded half).
__device__ __forceinline__ void dft8h(const v2f c[4], v2f y[8]) {
    const float s = 0.70710678118654752440f;
    v2f e0 = c[0] + c[2], e2 = c[0] - c[2];
    v2f j  = jrot<false>(c[2]);
    v2f e1 = c[0] + j, e3 = c[0] - j;
    v2f o0 = c[1] + c[3], o2 = c[1] - c[3];
    v2f jo = jrot<false>(c[3]);
    v2f o1 = c[1] + jo, o3 = c[1] - jo;

    v2f r1 = __builtin_shufflevector(o1, o1, 1, 0);
    o1 = s * (v2f){o1.x + r1.x, o1.y - r1.y};
    v2f r2 = __builtin_shufflevector(o2, o2, 1, 0);
    o2 = (v2f){r2.x, -r2.y};
    v2f r3 = __builtin_shufflevector(o3, o3, 1, 0);
    o3 = s * (v2f){r3.x - o3.x, -r3.y - o3.y};

    y[0] = e0 + o0; y[4] = e0 - o0;
    y[1] = e1 + o1; y[5] = e1 - o1;
    y[2] = e2 + o2; y[6] = e2 - o2;
    y[3] = e3 + o3; y[7] = e3 - o3;
}

// Stockham radix-8 stage: dst[j*8m + i + u*m] = W_N^{jm*u} * y[u]
// Computed twiddles (R3-proven: VALU is the cheap pipe here; a global table
// stalled the kernel on L2 latency — R7 post-mortem).  Base angle in
// REVOLUTIONS fed straight to v_sin/v_cos.
template<bool INV, int LGM>
__device__ __forceinline__ void stage8_write(v2f* lds, int tid, v2f y[8]) {
    const int m = 1 << LGM;
    const int jm = tid & ~(m - 1);
    float rev = (INV ? (1.0f / 2048.0f) : (-1.0f / 2048.0f)) * (float)jm;
    v2f w1 = { __builtin_amdgcn_cosf(rev), __builtin_amdgcn_sinf(rev) };
    v2f w2 = cmul(w1, w1);
    v2f w3 = cmul(w2, w1);
    v2f w4 = cmul(w2, w2);
    v2f w5 = cmul(w3, w2);
    v2f w6 = cmul(w3, w3);
    v2f w7 = cmul(w4, w3);
    int base = ((tid >> LGM) << (LGM + 3)) + (tid & (m - 1));
    int swb = base + (base >> 4);
    lds[swb + swoff(LGM, 0)] = y[0];
    lds[swb + swoff(LGM, 1)] = cmul(w1, y[1]);
    lds[swb + swoff(LGM, 2)] = cmul(w2, y[2]);
    lds[swb + swoff(LGM, 3)] = cmul(w3, y[3]);
    lds[swb + swoff(LGM, 4)] = cmul(w4, y[4]);
    lds[swb + swoff(LGM, 5)] = cmul(w5, y[5]);
    lds[swb + swoff(LGM, 6)] = cmul(w6, y[6]);
    lds[swb + swoff(LGM, 7)] = cmul(w7, y[7]);
}

__device__ __forceinline__ void read8(const v2f* lds, int swb, v2f c[8]) {
#pragma unroll
    for (int s = 0; s < 8; ++s) c[s] = lds[swb + 272 * s];
}

// gelu (tanh approx) on a pair
__device__ __forceinline__ v2f gelu2(v2f v) {
    v2f v2 = v * v;
    v2f q = v2 * 0.044715f + 1.0f;
    v2f z = v * q * 1.5957691216057308f;
    v2f e;
    e.x = __expf(z.x); e.y = __expf(z.y);
    v2f den = e + 1.0f;
    v2f r;
    r.x = __builtin_amdgcn_rcpf(den.x);
    r.y = __builtin_amdgcn_rcpf(den.y);
    return v - v * r;
}

// ---------------------------------------------------------------------------
// Embedding gather with 64x64 tile transpose: act[b][h][l] = emb[x[b][l]][h]
// ---------------------------------------------------------------------------
__global__ __launch_bounds__(256) void embed_kernel(const int* __restrict__ x,
                                                    const float* __restrict__ emb,
                                                    float* __restrict__ act)
{
    __shared__ float tile[64][65];
    int hb = blockIdx.x, lb = blockIdx.y, b = blockIdx.z;
    int h0 = hb * 64, l0 = lb * 64;
    int tid = threadIdx.x;
#pragma unroll
    for (int k = 0; k < 16; ++k) {
        int idx = (k << 8) + tid;
        int li = idx >> 6, hi = idx & 63;
        int xv = x[b * kL + l0 + li];
        tile[li][hi] = emb[(size_t)xv * kH + h0 + hi];
    }
    __syncthreads();
#pragma unroll
    for (int k = 0; k < 16; ++k) {
        int idx = (k << 8) + tid;
        int hi = idx >> 6, li = idx & 63;
        act[((size_t)b * kH + h0 + hi) * kL + l0 + li] = tile[li][hi];
    }
}

// ---------------------------------------------------------------------------
// SSM kernel K[h][l] + forward FFT -> Khat (pre-scaled by 1/2048).
// Phase in revolutions, exact f32 hi/lo split, v_sin/v_cos rev-input.
// grid: (h=512, layers); layer = layer0 + blockIdx.y
// ---------------------------------------------------------------------------
__global__ __launch_bounds__(256) void kcomp_kernel(const float* __restrict__ log_dt,
                                                    const float* __restrict__ A_log,
                                                    const float* __restrict__ A_imag,
                                                    const float* __restrict__ C_re,
                                                    const float* __restrict__ C_im,
                                                    v2f* __restrict__ Khat,
                                                    int layer0, int out_stride)
{
    __shared__ v2f lds[LDSZ];
    __shared__ float dre_s[kN], g2re_s[kN], g2im_s[kN], hi_s[kN], lo_s[kN];
    __shared__ v2f w256_s[kN];

    int h = blockIdx.x, tid = threadIdx.x;
    int layer = layer0 + blockIdx.y;
    int swbase = tid + (tid >> 4);
    const size_t po = (size_t)layer * kH + h;

    if (tid < kN) {
        int n = tid;
        float dt  = expf(log_dt[po]);
        float Are = -expf(A_log[po * kN + n]);
        float Aim = A_imag[po * kN + n];
        float dre = dt * Are;
        float dim = dt * Aim;
        float er = expf(dre);
        float sw, cw;
        sincosf(dim, &sw, &cw);
        float emr = er * cw - 1.0f, emi = er * sw;
        float inv = 1.0f / (Are * Are + Aim * Aim);
        float air = Are * inv, aii = -Aim * inv;
        float br = emr * air - emi * aii;
        float bi = emr * aii + emi * air;
        float cr = C_re[po * kN + n], ci = C_im[po * kN + n];
        dre_s[n]  = dre;
        g2re_s[n] = 2.0f * (cr * br - ci * bi);
        g2im_s[n] = 2.0f * (cr * bi + ci * br);
        double dimrev = (double)dim * (1.0 / TWO_PI);
        float drf = (float)dimrev;
        float hi = __uint_as_float(__float_as_uint(drf) & 0xFFFFF000u);
        hi_s[n] = hi;
        lo_s[n] = (float)(dimrev - (double)hi);
        float mag256 = __expf(dre * 256.0f);
        double r2 = dimrev * 256.0;
        r2 -= floor(r2);
        float fr2 = (float)r2;
        w256_s[n] = (v2f){mag256 * __builtin_amdgcn_cosf(fr2),
                          mag256 * __builtin_amdgcn_sinf(fr2)};
    }
    __syncthreads();

    // K at l = tid + 256*s  (matches FFT stage-1 register layout)
    float acc0 = 0.f, acc1 = 0.f, acc2 = 0.f, acc3 = 0.f;
    const float lf = (float)tid;
    for (int n = 0; n < kN; ++n) {
        float dre  = dre_s[n];
        float g2re = g2re_s[n], g2im = g2im_s[n];
        float t1 = hi_s[n] * lf;            // exact
        float r1 = t1 - floorf(t1);
        float rv = r1 + lo_s[n] * lf;
        rv -= floorf(rv);                   // revolutions in [0,1)
        float mag = __expf(dre * lf);
        float sp = __builtin_amdgcn_sinf(rv);
        float cp = __builtin_amdgcn_cosf(rv);
        float pzx = mag * cp, pzy = mag * sp;
        v2f w = w256_s[n];
        float tx;
        acc0 += g2re * pzx - g2im * pzy;
        tx = pzx * w.x - pzy * w.y; pzy = pzx * w.y + pzy * w.x; pzx = tx;
        acc1 += g2re * pzx - g2im * pzy;
        tx = pzx * w.x - pzy * w.y; pzy = pzx * w.y + pzy * w.x; pzx = tx;
        acc2 += g2re * pzx - g2im * pzy;
        tx = pzx * w.x - pzy * w.y; pzy = pzx * w.y + pzy * w.x; pzx = tx;
        acc3 += g2re * pzx - g2im * pzy;
    }

    {   // forward stage 1 from registers (upper half zero)
        v2f c[4], y[8];
        c[0] = (v2f){acc0, 0.f}; c[1] = (v2f){acc1, 0.f};
        c[2] = (v2f){acc2, 0.f}; c[3] = (v2f){acc3, 0.f};
        dft8h(c, y);
        stage8_write<false, 0>(lds, tid, y);
    }
    __syncthreads();
    {
        v2f c[8], y[8];
        read8(lds, swbase, c);
        __syncthreads();
        dft8<false>(c, y);
        stage8_write<false, 3>(lds, tid, y);
    }
    __syncthreads();
    {
        v2f c[8], y[8];
        read8(lds, swbase, c);
        __syncthreads();
        dft8<false>(c, y);
        stage8_write<false, 6>(lds, tid, y);
    }
    __syncthreads();
    {   // radix-4 final stage (m=512, j=0) -> global, natural order, *1/2048
        const float invn = 1.0f / (float)kNFFT;
        v2f* outp = Khat + (size_t)(layer * out_stride + h) * kNFFT;
#pragma unroll
        for (int r = 0; r < 2; ++r) {
            v2f c0 = lds[swbase + 272 * r];
            v2f c1 = lds[swbase + 272 * r + 544];
            v2f c2 = lds[swbase + 272 * r + 1088];
            v2f c3 = lds[swbase + 272 * r + 1632];
            v2f t0 = c0 + c2, t1 = c0 - c2;
            v2f t2 = c1 + c3, t3 = c1 - c3;
            v2f j3 = jrot<false>(t3);
            int q = tid + (r << 8);
            outp[q]        = (t0 + t2) * invn;
            outp[q + 512]  = (t1 + j3) * invn;
            outp[q + 1024] = (t0 - t2) * invn;
            outp[q + 1536] = (t1 - j3) * invn;
        }
    }
}

// ---------------------------------------------------------------------------
// Per-layer conv (R3-proven codegen): rows (2*pair,h),(2*pair+1,h) packed as
// one complex signal; us[] in registers; FFT -> *Khat -> IFFT -> +D*u -> gelu.
// grid: (h=512, pair=16), 256 threads
// ---------------------------------------------------------------------------
__global__ __launch_bounds__(256) void conv_kernel(float* __restrict__ act,
                                                   const v2f* __restrict__ Khat,
                                                   const float* __restrict__ Dvec)
{
    __shared__ v2f lds[LDSZ];

    int h = blockIdx.x, pair = blockIdx.y, tid = threadIdx.x;
    int swbase = tid + (tid >> 4);
    float* rowa = act + ((size_t)(2 * pair) * kH + h) * kL;
    float* rowb = rowa + (size_t)kH * kL;

    v2f us[4];
#pragma unroll
    for (int s = 0; s < 4; ++s) {
        int l = tid + (s << 8);
        us[s] = (v2f){rowa[l], rowb[l]};
    }
    {
        v2f y[8];
        dft8h(us, y);
        stage8_write<false, 0>(lds, tid, y);
    }
    __syncthreads();
    {
        v2f c[8], y[8];
        read8(lds, swbase, c);
        __syncthreads();
        dft8<false>(c, y);
        stage8_write<false, 3>(lds, tid, y);
    }
    __syncthreads();
    {
        v2f c[8], y[8];
        read8(lds, swbase, c);
        __syncthreads();
        dft8<false>(c, y);
        stage8_write<false, 6>(lds, tid, y);
    }
    __syncthreads();
    {
        v2f cc[2][4];
#pragma unroll
        for (int r = 0; r < 2; ++r)
#pragma unroll
            for (int s = 0; s < 4; ++s)
                cc[r][s] = lds[swbase + 272 * r + 544 * s];
        __syncthreads();
        const v2f* kh = Khat + (size_t)h * kNFFT;
#pragma unroll
        for (int r = 0; r < 2; ++r) {
            v2f t0 = cc[r][0] + cc[r][2], t1 = cc[r][0] - cc[r][2];
            v2f t2 = cc[r][1] + cc[r][3], t3 = cc[r][1] - cc[r][3];
            v2f j3 = jrot<false>(t3);
            int q = tid + (r << 8);
            int swq = swbase + 272 * r;
            lds[swq]        = cmul(t0 + t2, kh[q]);
            lds[swq + 544]  = cmul(t1 + j3, kh[q + 512]);
            lds[swq + 1088] = cmul(t0 - t2, kh[q + 1024]);
            lds[swq + 1632] = cmul(t1 - j3, kh[q + 1536]);
        }
    }
    __syncthreads();
    {
        v2f c[8], y[8];
        read8(lds, swbase, c);
        __syncthreads();
        dft8<true>(c, y);
        stage8_write<true, 0>(lds, tid, y);
    }
    __syncthreads();
    {
        v2f c[8], y[8];
        read8(lds, swbase, c);
        __syncthreads();
        dft8<true>(c, y);
        stage8_write<true, 3>(lds, tid, y);
    }
    __syncthreads();
    {
        v2f c[8], y[8];
        read8(lds, swbase, c);
        __syncthreads();
        dft8<true>(c, y);
        stage8_write<true, 6>(lds, tid, y);
    }
    __syncthreads();
    {
        float Dh = Dvec[h];
#pragma unroll
        for (int r = 0; r < 2; ++r) {
            v2f c0 = lds[swbase + 272 * r];
            v2f c1 = lds[swbase + 272 * r + 544];
            v2f c2 = lds[swbase + 272 * r + 1088];
            v2f c3 = lds[swbase + 272 * r + 1632];
            v2f t0 = c0 + c2, t1 = c0 - c2;
            v2f t2 = c1 + c3, t3 = c1 - c3;
            v2f j3 = jrot<false>(t3);
            v2f y0 = t0 + t2;
            v2f y1 = t1 - j3;
            int l0 = tid + (r << 8);
            v2f g0 = gelu2(y0 + Dh * us[r]);
            v2f g1 = gelu2(y1 + Dh * us[r + 2]);
            rowa[l0]       = g0.x;
            rowb[l0]       = g0.y;
            rowa[l0 + 512] = g1.x;
            rowb[l0 + 512] = g1.y;
        }
    }
}

// ---------------------------------------------------------------------------
// Last-layer conv fused with mean-pool + fc-scale.  Same FFT body; epilogue
// accumulates gelu outputs, block-reduces, and stores ONE pre-scaled partial
// per (pair,h) — NO atomics (R7 post-mortem: 16K same-address atomicAdds cost
// ~120 us).  A tiny reduce kernel finishes the sum over h.
// grid: (h=512, pair=16), 256 threads
// ---------------------------------------------------------------------------
__global__ __launch_bounds__(256) void conv_final(const float* __restrict__ act,
                                                  const v2f* __restrict__ Khat,
                                                  const float* __restrict__ Dvec,
                                                  const float* __restrict__ fc_w,
                                                  v2f* __restrict__ partials)
{
    __shared__ v2f lds[LDSZ];
    __shared__ v2f wred[4];

    int h = blockIdx.x, pair = blockIdx.y, tid = threadIdx.x;
    int swbase = tid + (tid >> 4);
    const float* rowa = act + ((size_t)(2 * pair) * kH + h) * kL;
    const float* rowb = rowa + (size_t)kH * kL;

    v2f us[4];
#pragma unroll
    for (int s = 0; s < 4; ++s) {
        int l = tid + (s << 8);
        us[s] = (v2f){rowa[l], rowb[l]};
    }
    {
        v2f y[8];
        dft8h(us, y);
        stage8_write<false, 0>(lds, tid, y);
    }
    __syncthreads();
    {
        v2f c[8], y[8];
        read8(lds, swbase, c);
        __syncthreads();
        dft8<false>(c, y);
        stage8_write<false, 3>(lds, tid, y);
    }
    __syncthreads();
    {
        v2f c[8], y[8];
        read8(lds, swbase, c);
        __syncthreads();
        dft8<false>(c, y);
        stage8_write<false, 6>(lds, tid, y);
    }
    __syncthreads();
    {
        v2f cc[2][4];
#pragma unroll
        for (int r = 0; r < 2; ++r)
#pragma unroll
            for (int s = 0; s < 4; ++s)
                cc[r][s] = lds[swbase + 272 * r + 544 * s];
        __syncthreads();
        const v2f* kh = Khat + (size_t)h * kNFFT;
#pragma unroll
        for (int r = 0; r < 2; ++r) {
            v2f t0 = cc[r][0] + cc[r][2], t1 = cc[r][0] - cc[r][2];
            v2f t2 = cc[r][1] + cc[r][3], t3 = cc[r][1] - cc[r][3];
            v2f j3 = jrot<false>(t3);
            int q = tid + (r << 8);
            int swq = swbase + 272 * r;
            lds[swq]        = cmul(t0 + t2, kh[q]);
            lds[swq + 544]  = cmul(t1 + j3, kh[q + 512]);
            lds[swq + 1088] = cmul(t0 - t2, kh[q + 1024]);
            lds[swq + 1632] = cmul(t1 - j3, kh[q + 1536]);
        }
    }
    __syncthreads();
    {
        v2f c[8], y[8];
        read8(lds, swbase, c);
        __syncthreads();
        dft8<true>(c, y);
        stage8_write<true, 0>(lds, tid, y);
    }
    __syncthreads();
    {
        v2f c[8], y[8];
        read8(lds, swbase, c);
        __syncthreads();
        dft8<true>(c, y);
        stage8_write<true, 3>(lds, tid, y);
    }
    __syncthreads();
    {
        v2f c[8], y[8];
        read8(lds, swbase, c);
        __syncthreads();
        dft8<true>(c, y);
        stage8_write<true, 6>(lds, tid, y);
    }
    __syncthreads();
    v2f p = (v2f){0.f, 0.f};
    {
        float Dh = Dvec[h];
#pragma unroll
        for (int r = 0; r < 2; ++r) {
            v2f c0 = lds[swbase + 272 * r];
            v2f c1 = lds[swbase + 272 * r + 544];
            v2f c2 = lds[swbase + 272 * r + 1088];
            v2f c3 = lds[swbase + 272 * r + 1632];
            v2f t0 = c0 + c2, t1 = c0 - c2;
            v2f t2 = c1 + c3, t3 = c1 - c3;
            v2f j3 = jrot<false>(t3);
            v2f y0 = t0 + t2;
            v2f y1 = t1 - j3;
            p += gelu2(y0 + Dh * us[r]);
            p += gelu2(y1 + Dh * us[r + 2]);
        }
    }
    // block reduce (64-lane waves), one plain store per wg
#pragma unroll
    for (int off = 32; off > 0; off >>= 1) {
        p.x += __shfl_down(p.x, off);
        p.y += __shfl_down(p.y, off);
    }
    if ((tid & 63) == 0) wred[tid >> 6] = p;
    __syncthreads();
    if (tid == 0) {
        v2f t = wred[0] + wred[1] + wred[2] + wred[3];
        float scale = fc_w[h] * (1.0f / (float)kL);
        partials[(size_t)pair * kH + h] = t * scale;
    }
}

// ---------------------------------------------------------------------------
// Final reduction: out[2p], out[2p+1] = sum_h partials[p][h] + bias.
// grid: 16 (one per pair), 256 threads.
// ---------------------------------------------------------------------------
__global__ __launch_bounds__(256) void reduce_kernel(const v2f* __restrict__ partials,
                                                     const float* __restrict__ fc_b,
                                                     float* __restrict__ out)
{
    __shared__ v2f wred[4];
    int pair = blockIdx.x, tid = threadIdx.x;
    v2f p = partials[(size_t)pair * kH + tid] + partials[(size_t)pair * kH + tid + 256];
#pragma unroll
    for (int off = 32; off > 0; off >>= 1) {
        p.x += __shfl_down(p.x, off);
        p.y += __shfl_down(p.y, off);
    }
    if ((tid & 63) == 0) wred[tid >> 6] = p;
    __syncthreads();
    if (tid == 0) {
        v2f t = wred[0] + wred[1] + wred[2] + wred[3];
        float bias = fc_b[0];
        out[2 * pair]     = t.x + bias;
        out[2 * pair + 1] = t.y + bias;
    }
}

// ---------------------------------------------------------------------------
extern "C" void kernel_launch(void* const* d_in, const int* in_sizes, int n_in,
                              void* d_out, int out_size, void* d_ws, size_t ws_size,
                              hipStream_t stream)
{
    const int*   x         = (const int*)d_in[0];
    const float* embedding = (const float*)d_in[1];
    const float* log_dt    = (const float*)d_in[2];
    const float* A_log     = (const float*)d_in[3];
    const float* A_imag    = (const float*)d_in[4];
    const float* C_re      = (const float*)d_in[5];
    const float* C_im      = (const float*)d_in[6];
    const float* Dv        = (const float*)d_in[7];
    const float* fc_w      = (const float*)d_in[8];
    const float* fc_b      = (const float*)d_in[9];
    float* out = (float*)d_out;

    char* ws = (char*)d_ws;
    const size_t act_bytes  = (size_t)kB * kH * kL * sizeof(float);       // 64 MiB
    const size_t khat_bytes = (size_t)kH * kNFFT * sizeof(float) * 2;     // 8 MiB / layer
    float* act  = (float*)ws;
    v2f*   Khat = (v2f*)(ws + act_bytes);

    const bool multi = ws_size >= act_bytes + kNL * khat_bytes;           // 96 MiB

    embed_kernel<<<dim3(8, 16, 32), 256, 0, stream>>>(x, embedding, act);

    if (multi) {
        // partials (64 KB) alias Khat layer-0's region: layer 0's Khat is dead
        // by the time conv_final (which reads only layer 3's slot) writes them.
        v2f* partials = Khat;
        kcomp_kernel<<<dim3(kH, kNL), 256, 0, stream>>>(log_dt, A_log, A_imag,
                                                        C_re, C_im, Khat, 0, kH);
        for (int layer = 0; layer < kNL - 1; ++layer) {
            conv_kernel<<<dim3(kH, kB / 2), 256, 0, stream>>>(
                act, Khat + (size_t)layer * kH * kNFFT, Dv + layer * kH);
        }
        conv_final<<<dim3(kH, kB / 2), 256, 0, stream>>>(
            act, Khat + (size_t)(kNL - 1) * kH * kNFFT,
            Dv + (kNL - 1) * kH, fc_w, partials);
        reduce_kernel<<<dim3(kB / 2), 256, 0, stream>>>(partials, fc_b, out);
    } else {
        // fallback: single Khat slot; partials in their own region after it
        v2f* partials = (v2f*)(ws + act_bytes + khat_bytes);
        for (int layer = 0; layer < kNL - 1; ++layer) {
            kcomp_kernel<<<dim3(kH, 1), 256, 0, stream>>>(log_dt, A_log, A_imag,
                                                          C_re, C_im, Khat, layer, 0);
            conv_kernel<<<dim3(kH, kB / 2), 256, 0, stream>>>(act, Khat, Dv + layer * kH);
        }
        kcomp_kernel<<<dim3(kH, 1), 256, 0, stream>>>(log_dt, A_log, A_imag,
                                                      C_re, C_im, Khat, kNL - 1, 0);
        conv_final<<<dim3(kH, kB / 2), 256, 0, stream>>>(act, Khat,
                                                         Dv + (kNL - 1) * kH, fc_w, partials);
        reduce_kernel<<<dim3(kB / 2), 256, 0, stream>>>(partials, fc_b, out);
    }
}